// Round 24
// baseline (106.580 us; speedup 1.0000x reference)
//
#include <hip/hip_runtime.h>
#include <hip/hip_bf16.h>

// ---------------------------------------------------------------------------
// DropBlock fused dual-conv, LIST-COMPACTED implicit GEMM (half FLOPs),
// m201-style 8-PHASE schedule (T2+T3+T4+T5), single round.
//   Tile: 256 list rows x 256 branch channels; BK=64; 36 K-tiles; 18 iters.
//   512 thr = 8 waves (wm=wave>>2 in {0,1}: 128 rows; wn=wave&3: 64 ch).
//   LDS 128 KiB = 2 parity buffers x {Ah0,Ah1,Bh0,Bh1} x 16 KiB.
// Phase p of iter i (u=2i par0, v=2i+1 par1, t2=min(u+2,35), t3=min(u+3,35)):
//   {ds-reads for this phase's quadrant; stage 1 half (2 gll16); BAR;
//    lgkm(0)+schedbar; setprio1; 16 MFMA; setprio0; [VM(4) @P4,P8]; BAR}
//   P1:(u,mh0,ks0)+B(u,ks0), stg Ah0(v) | P2:(u,mh0,ks1)+B(u,ks1), stg Ah1(v)
//   P3:(u,mh1,ks0), stg Bh0(t2) | P4:(u,mh1,ks1), stg Bh1(t2), VM4
//   P5:(v,mh0,ks0)+B(v,ks0), stg Ah0(t2) | P6:(v,mh0,ks1)+B(v,ks1), stg Ah1(t2)
//   P7:(v,mh1,ks0), stg Bh0(t3) | P8:(v,mh1,ks1), stg Bh1(t3), VM4
// Ledger (2 ops/half, FIFO): VM(4)@P4 retires {Bh0,Bh1(v)@prevP7P8,
//   Ah0,Ah1(v)@P1P2} -> tile v complete before P5. VM(4)@P8 retires
//   {B(t2)@P3P4, A(t2)@P5P6} -> t2 complete before next P1. Never <4 in flight.
// Region-free: each stage target's last read is >=1 phase-barrier earlier
//   (B-par read P1P2/P5P6; Ah0 P1P2/P5P6; Ah1 P3P4/P7P8). Tail dups clamp to
//   tile35: identical bytes or dead regions. Prologue stages tile0 (4 halves)
//   + B(1) (2 halves), VM(4) retires tile0, BAR.
// Swizzle (128B rows, 8x16B chunks): phys p holds logical p^(row&7); A source
//   pre-swizzled via swz=((tid&7)^((tid>>3)&7))<<4; wt pre-blocked
//   [36t][2bn][2half][128ch][8p][16B] so B staging is linear.
// ws: [0,4) cntB | [4,8) cntA | [65536,+29491200) xt bf16 [64][30][30][256]
//     | [29556736,+2359296) wt | [31916032,+200704) listA
//     | [32116736,+200704) listB
// ---------------------------------------------------------------------------

typedef __bf16  bf16x8 __attribute__((ext_vector_type(8)));
typedef float   f32x4  __attribute__((ext_vector_type(4)));
typedef short   short8 __attribute__((ext_vector_type(8)));
typedef unsigned int u32;
typedef unsigned short u16;

#define XT_OFF     65536
#define WT_OFF     29556736
#define LISTA_OFF  31916032
#define LISTB_OFF  32116736

__device__ __forceinline__ u16 f2bf(float v) {
    u32 u = __float_as_uint(v);
    u32 r = (u + 0x7FFFu + ((u >> 16) & 1u)) >> 16;
    return (u16)r;
}

__device__ __forceinline__ void gll16(const void* g, void* l) {
    __builtin_amdgcn_global_load_lds(
        (const __attribute__((address_space(1))) u32*)g,
        (__attribute__((address_space(3))) u32*)l, 16, 0, 0);
}

// ---------------- fused prep: xt transform + wt blocks + mask/lists --------
__global__ void prep_kernel(const float* __restrict__ x,
                            const float* __restrict__ wl,
                            const float* __restrict__ wp,
                            const float* __restrict__ mu,
                            u16* __restrict__ xt, u16* __restrict__ wt,
                            int* __restrict__ listA, int* __restrict__ listB,
                            int* __restrict__ cntB, int* __restrict__ cntA) {
    int b = blockIdx.x, tid = threadIdx.x;
    if (b < 1920) {                                   // ---- xt: 64*30 rows
        int n = b / 30, oh = b % 30;
        u16* row = xt + (size_t)(n * 30 + oh) * 30 * 256;
        if (oh == 0 || oh == 29) {                    // halo rows: full zero
            u32* r32 = (u32*)row;
            #pragma unroll
            for (int i = 0; i < 15; ++i) r32[i * 256 + tid] = 0;
            return;
        }
        __shared__ u16 sm[7168];                      // [28 w][256 c]
        int h = oh - 1;
        const float* src = x + ((size_t)(n * 256 + tid) * 28 + h) * 28;
        float f[28];
        #pragma unroll
        for (int q = 0; q < 7; ++q) {
            float4 v = *(const float4*)(src + q * 4);
            f[q * 4 + 0] = v.x; f[q * 4 + 1] = v.y;
            f[q * 4 + 2] = v.z; f[q * 4 + 3] = v.w;
        }
        #pragma unroll
        for (int w = 0; w < 28; ++w)
            sm[w * 256 + tid] = f2bf(f[w]);           // 2-way banks: free
        __syncthreads();
        u32* r32 = (u32*)row;
        if (tid < 128) r32[tid] = 0;                  // halo col ow=0
        else           r32[29 * 128 + (tid - 128)] = 0;   // halo col ow=29
        const u32* s32 = (const u32*)sm;
        u32* dst = r32 + 128;                         // ow=1..28 contiguous
        #pragma unroll
        for (int k = 0; k < 14; ++k)                  // 3584 u32 coalesced
            dst[k * 256 + tid] = s32[k * 256 + tid];
    } else if (b < 2048) {                            // ---- wt (coalesced)
        // stage 4 out-ch rows coalesced -> LDS bf16 -> scatter to blocked
        // layout [36t][2bn][2half][128ch][8p][8jj], p holds c-chunk p^(ch&7).
        __shared__ u16 wsm[9216];                     // [4 rl][2304 = c*9+kk]
        int wb = b - 1920;                            // 0..127
        int bn = wb >> 6, rowg = (wb & 63) * 4;       // ch rowg..rowg+3
        const float* wsrc = (bn ? wp : wl) + (size_t)rowg * 2304;
        const f32x4* s4 = (const f32x4*)wsrc;         // 2304 float4
        #pragma unroll
        for (int i = 0; i < 9; ++i) {
            int q = i * 256 + tid;
            f32x4 v = s4[q];
            #pragma unroll
            for (int cmp = 0; cmp < 4; ++cmp)
                wsm[q * 4 + cmp] = f2bf(v[cmp]);
        }
        __syncthreads();
        u32* wo = (u32*)wt;
        #pragma unroll
        for (int w = 0; w < 18; ++w) {                // 4608 u32 per block
            int idx = w * 256 + tid;
            int jj2 = idx & 3;                        // jj = jj2*2
            int p   = (idx >> 2) & 7;
            int tt  = idx >> 5;                       // 0..143
            int t = tt % 36, rl = tt / 36;
            int ch = rowg + rl;                       // 0..255
            int c0 = (t & 3) * 64 + ((p ^ (ch & 7)) << 3) + jj2 * 2;
            int e0 = rl * 2304 + c0 * 9 + (t >> 2);
            u32 val = (u32)wsm[e0] | ((u32)wsm[e0 + 9] << 16);
            wo[(size_t)(t * 2 + bn) * 8192 + (ch >> 7) * 4096
               + (ch & 127) * 32 + p * 4 + jj2] = val;
        }
    } else {                                          // ---- mask + list build
        __shared__ int lsum[4];
        __shared__ int basB, basA;
        int m = (b - 2048) * 256 + tid;               // 196*256 exact
        int n = m / 784, rem = m % 784;
        int h = rem / 28, w = rem % 28;
        const float g = (float)(0.1 / 49.0);
        const float* un = mu + n * 784;
        int p = 0;
        for (int dy = -3; dy <= 3; ++dy) {
            int hh = h + dy;
            if (hh < 0 || hh >= 28) continue;
            for (int dx = -3; dx <= 3; ++dx) {
                int ww = w + dx;
                if (ww < 0 || ww >= 28) continue;
                p |= (un[hh * 28 + ww] < g) ? 1 : 0;
            }
        }
        unsigned long long ball = __ballot(p);
        int wid = tid >> 6, ln = tid & 63;
        if (ln == 0) lsum[wid] = __popcll(ball);
        __syncthreads();
        if (tid == 0) {
            int tB = lsum[0] + lsum[1] + lsum[2] + lsum[3];
            basB = atomicAdd(cntB, tB);
            basA = atomicAdd(cntA, 256 - tB);
        }
        __syncthreads();
        int offB = 0, offA = 0;
        for (int i = 0; i < wid; ++i) { offB += lsum[i]; offA += 64 - lsum[i]; }
        int rank1 = __popcll(ball & ((1ULL << ln) - 1));
        int rank0 = ln - rank1;
        if (p) listB[basB + offB + rank1] = m;
        else   listA[basA + offA + rank0] = m;
    }
}

// ---------------- 8-phase list-compacted implicit-GEMM conv ----------------
__global__ __launch_bounds__(512, 2)
void conv_kernel(const char* __restrict__ xt,    // bf16 padded NHWC (bytes)
                 const char* __restrict__ wt,    // bf16 blocked weights
                 const int* __restrict__ listA,
                 const int* __restrict__ listB,
                 const int* __restrict__ dropped,   // = cntB
                 float* __restrict__ out) {
    __shared__ char smem[131072];                 // 2 parity x 64 KiB
    const int tid = threadIdx.x;
    const int lb = (blockIdx.x & 7) * 25 + (blockIdx.x >> 3);  // 200 = 8*25
    const int cB = *dropped;
    const int cA = 50176 - cB;
    const int naT = (cA + 255) >> 8;
    const int nbT = (cB + 255) >> 8;
    if (lb >= naT + nbT) return;             // block-uniform exit
    const int branch = (lb >= naT) ? 1 : 0;
    const int tix = branch ? (lb - naT) : lb;
    const int cnt = branch ? cB : cA;
    const int* lst = branch ? listB : listA;
    const int lane = tid & 63, wave = tid >> 6;
    const int lane15 = lane & 15, grp = lane >> 4;
    const int wm = wave >> 2, wn = wave & 3; // per-wave 128 rows x 64 ch

    // --- A staging source bases; op q = h*2+j: row = h*128+j*64+(tid>>3) ---
    long pbA[4];
    {
        int swz = ((tid & 7) ^ ((tid >> 3) & 7)) << 4;
        #pragma unroll
        for (int q = 0; q < 4; ++q) {
            int r = (q >> 1) * 128 + (q & 1) * 64 + (tid >> 3);
            int idx = tix * 256 + r;
            if (idx >= cnt) idx = cnt - 1;   // ragged-tail clamp (dup rows)
            int m = lst[idx];
            int n = m / 784, rem = m % 784;
            pbA[q] = (long)(((n * 30 + rem / 28 + 1) * 30 + (rem % 28 + 1)) * 512
                            + swz);
        }
    }

    f32x4 acc[8][4];
    #pragma unroll
    for (int i = 0; i < 8; ++i)
        #pragma unroll
        for (int j = 0; j < 4; ++j)
            acc[i][j] = (f32x4){0.f, 0.f, 0.f, 0.f};

    const int xA = lane15 & 7;                            // row&7 / ch&7
    int axk[2];                                           // k-chunk offsets
    axk[0] = (grp ^ xA) << 4;                             // ks0
    axk[1] = ((4 + grp) ^ xA) << 4;                       // ks1
    const int aBase = wm * 16384 + (lane15 << 7);
    const int bBase = 32768 + ((wn >> 1) << 14) + (((wn & 1) * 64 + lane15) << 7);

#define AON(TC) ((long)((TC) >> 2) / 3 * 15360 + (long)(((TC) >> 2) % 3) * 512 \
                 - 15872 + (long)(((TC) & 3) << 7))
#define DS_A(dst, PAR, MH, KS) { const char* s_ = smem + (PAR) * 65536;     \
        _Pragma("unroll")                                                   \
        for (int f = 0; f < 4; ++f)                                         \
            dst[f] = *(const bf16x8*)(s_ + aBase + (MH) * 8192 + f * 2048   \
                                      + axk[KS]); }
#define DS_B(dst, PAR, KS) { const char* s_ = smem + (PAR) * 65536;         \
        _Pragma("unroll")                                                   \
        for (int fn = 0; fn < 4; ++fn)                                      \
            dst[fn] = *(const bf16x8*)(s_ + bBase + fn * 2048 + axk[KS]); }
#define STG_AH(TC, H, PAR) { char* d_ = smem + (PAR) * 65536 + (H) * 16384; \
        const long ao_ = AON(TC);                                           \
        gll16(xt + pbA[(H) * 2 + 0] + ao_, d_ + (tid << 4));                \
        gll16(xt + pbA[(H) * 2 + 1] + ao_, d_ + 8192 + (tid << 4)); }
#define STG_BH(TC, H, PAR) {                                                \
        const char* s_ = wt + ((size_t)((TC) * 2 + branch) << 15)           \
                         + ((H) << 14);                                     \
        char* d_ = smem + (PAR) * 65536 + 32768 + (H) * 16384;              \
        gll16(s_ + (tid << 4), d_ + (tid << 4));                            \
        gll16(s_ + 8192 + (tid << 4), d_ + 8192 + (tid << 4)); }
#define MMc(BASE, AV, BV) { __builtin_amdgcn_s_setprio(1);                  \
        _Pragma("unroll")                                                   \
        for (int fm = 0; fm < 4; ++fm)                                      \
            _Pragma("unroll")                                               \
            for (int fn = 0; fn < 4; ++fn)                                  \
                acc[(BASE) + fm][fn] = __builtin_amdgcn_mfma_f32_16x16x32_bf16( \
                    AV[fm], BV[fn], acc[(BASE) + fm][fn], 0, 0, 0);         \
        __builtin_amdgcn_s_setprio(0); }
#define LGKM0   { asm volatile("s_waitcnt lgkmcnt(0)" ::: "memory");        \
                  __builtin_amdgcn_sched_barrier(0); }
#define VM4     { asm volatile("s_waitcnt vmcnt(4)" ::: "memory");          \
                  __builtin_amdgcn_sched_barrier(0); }
#define BAR     asm volatile("s_barrier" ::: "memory")

    bf16x8 av[4], bv0[4], bv1[4];

    // --- prologue: tile0 (4 halves) + B(1) (2 halves); retire tile0 ---
    STG_AH(0, 0, 0); STG_AH(0, 1, 0);
    STG_BH(0, 0, 0); STG_BH(0, 1, 0);
    STG_BH(1, 0, 1); STG_BH(1, 1, 1);
    VM4;                              // 12 -> 4: tile0 landed; B(1) in flight
    BAR;

    for (int i = 0; i < 18; ++i) {
        const int v = 2 * i + 1;
        int t2 = 2 * i + 2; if (t2 > 35) t2 = 35;
        int t3 = 2 * i + 3; if (t3 > 35) t3 = 35;
        // P1: (u,mh0,ks0) + B(u,ks0); stage Ah0(v)
        DS_A(av, 0, 0, 0); DS_B(bv0, 0, 0); STG_AH(v, 0, 1);
        BAR; LGKM0; MMc(0, av, bv0); BAR;
        // P2: (u,mh0,ks1) + B(u,ks1); stage Ah1(v)
        DS_A(av, 0, 0, 1); DS_B(bv1, 0, 1); STG_AH(v, 1, 1);
        BAR; LGKM0; MMc(0, av, bv1); BAR;
        // P3: (u,mh1,ks0); stage Bh0(t2)
        DS_A(av, 0, 1, 0); STG_BH(t2, 0, 0);
        BAR; LGKM0; MMc(4, av, bv0); BAR;
        // P4: (u,mh1,ks1); stage Bh1(t2); VM4 retires tile v
        DS_A(av, 0, 1, 1); STG_BH(t2, 1, 0);
        BAR; LGKM0; MMc(4, av, bv1); VM4; BAR;
        // P5: (v,mh0,ks0) + B(v,ks0); stage Ah0(t2)
        DS_A(av, 1, 0, 0); DS_B(bv0, 1, 0); STG_AH(t2, 0, 0);
        BAR; LGKM0; MMc(0, av, bv0); BAR;
        // P6: (v,mh0,ks1) + B(v,ks1); stage Ah1(t2)
        DS_A(av, 1, 0, 1); DS_B(bv1, 1, 1); STG_AH(t2, 1, 0);
        BAR; LGKM0; MMc(0, av, bv1); BAR;
        // P7: (v,mh1,ks0); stage Bh0(t3)
        DS_A(av, 1, 1, 0); STG_BH(t3, 0, 1);
        BAR; LGKM0; MMc(4, av, bv0); BAR;
        // P8: (v,mh1,ks1); stage Bh1(t3); VM4 retires tile t2
        DS_A(av, 1, 1, 1); STG_BH(t3, 1, 1);
        BAR; LGKM0; MMc(4, av, bv1); VM4; BAR;
    }

    // --- epilogue: per-wave LDS transpose -> coalesced scaled stores ---
    float scale = 50176.0f / (float)(50176 - cB);
    float* ep = (float*)smem + wave * 2080;      // private [32][65] f32
    __syncthreads();    // full vm/lgkm drain (incl. tail dups) + barrier
    #pragma unroll
    for (int rr = 0; rr < 4; ++rr) {
        const int r2 = rr & 1;        // 32-channel half of this wave's 64
        const int mh = rr >> 1;       // row half (64 of 128)
        #pragma unroll
        for (int fm2 = 0; fm2 < 4; ++fm2)
            #pragma unroll
            for (int f2 = 0; f2 < 2; ++f2)
                #pragma unroll
                for (int j = 0; j < 4; ++j)
                    ep[(f2 * 16 + lane15) * 65 + fm2 * 16 + grp * 4 + j] =
                        acc[mh * 4 + fm2][r2 * 2 + f2][j];
        __syncthreads();
        {
            int gidx = tix * 256 + wm * 128 + mh * 64 + lane;
            if (gidx < cnt) {
                int m = lst[gidx];
                int n = m / 784, rem = m % 784;
                size_t ob = (size_t)n * 200704 + rem;
                #pragma unroll
                for (int ch = 0; ch < 32; ++ch) {
                    int c = wn * 64 + r2 * 32 + ch;
                    out[ob + (size_t)c * 784] = ep[ch * 65 + lane] * scale;
                }
            }
        }
        __syncthreads();
    }
#undef AON
#undef DS_A
#undef DS_B
#undef STG_AH
#undef STG_BH
#undef MMc
#undef LGKM0
#undef VM4
#undef BAR
}

// ---------------------------------------------------------------------------
extern "C" void kernel_launch(void* const* d_in, const int* in_sizes, int n_in,
                              void* d_out, int out_size, void* d_ws, size_t ws_size,
                              hipStream_t stream) {
    const float* x  = (const float*)d_in[0];
    const float* wl = (const float*)d_in[1];
    const float* wp = (const float*)d_in[2];
    const float* mu = (const float*)d_in[3];
    float* out = (float*)d_out;
    char* ws = (char*)d_ws;

    int* cntB = (int*)ws;                     // = dropped
    int* cntA = (int*)(ws + 4);
    u16* xt = (u16*)(ws + XT_OFF);
    u16* wt = (u16*)(ws + WT_OFF);
    int* listA = (int*)(ws + LISTA_OFF);
    int* listB = (int*)(ws + LISTB_OFF);

    hipMemsetAsync(ws, 0, 8, stream);

    prep_kernel<<<2244, 256, 0, stream>>>(x, wl, wp, mu, xt, wt,
                                          listA, listB, cntB, cntA);
    conv_kernel<<<200, 512, 0, stream>>>((const char*)xt, (const char*)wt,
                                         listA, listB, cntB, out);
}